// Round 3
// baseline (195.956 us; speedup 1.0000x reference)
//
#include <hip/hip_runtime.h>
#include <hip/hip_cooperative_groups.h>

namespace cg = cooperative_groups;

// DisjointDense: out[b] = x[b] @ W[sel[b]] + Bw[sel[b]]
// B=4096, D_IN=256, D_OUT=256, N_DISJOINT=64, all fp32.
//
// R14: fused cooperative kernel, de-risked after R13's silent launch
// rejection (absmax == max|ref| -> out never written -> launch error was
// swallowed). Changes vs R13:
//  - grid 512 (not 1024): needs 2 blocks/CU vs the guaranteed 4/CU bound,
//    2x margin on the cooperative occupancy check that likely rejected R13.
//  - host-side capture-safe guards (cooperative-launch attr + occupancy
//    query) before attempting the cooperative launch.
//  - checked fallback to the proven R12 3-dispatch path (memset + dd_prep +
//    dd_compute, 86.9us) if cooperative is unavailable or errors.
//  - __threadfence() release before grid sync #2 (cross-XCD visibility
//    insurance for plain buckets/xbs stores).
// Fused mapping: 512 blocks = [task:3][d:6]; prep = blocks 0..127 (phase A:
// ballot + x->bf16 into regs + LDS hist) overlapped with W-fragment prologue
// on blocks 128..511; block 0 zeroes counts; sync#1; prep phase B (global
// slot atomics, bucket/xbs stores, own W frags L2-warm); sync#2; compute
// identical to R12 but row-stride 64 (2 row-tiles).

#define NBLK 64
#define BCAP 1024   // rowid capacity per bucket
#define BCAPX 256   // xbs row capacity per bucket (max real count ~92)
#define CPAD 16
#define PREP_BLOCKS 128

typedef __attribute__((ext_vector_type(8))) short bf16x8;
typedef __attribute__((ext_vector_type(4))) float f32x4;

__device__ __forceinline__ unsigned short f2bf(float f) {
    unsigned u = __float_as_uint(f);
    u += 0x7FFFu + ((u >> 16) & 1u);       // round-to-nearest-even
    return (unsigned short)(u >> 16);
}

// ---------------- fused cooperative kernel (512 blocks) ----------------
__global__ __launch_bounds__(256, 4) void dd_fused(
    const float* __restrict__ x,              // [4096, 256]
    const float* __restrict__ onehot,         // [4096, 64]
    const float* __restrict__ W,              // [64, 256, 256] (d, k, col)
    const float* __restrict__ Bw,             // [64, 256]
    int* __restrict__ counts,                 // [64*CPAD]
    int* __restrict__ buckets,                // [64, BCAP]
    unsigned short* __restrict__ xbs,         // [64, BCAPX, 256] bf16
    float* __restrict__ out)                  // [4096, 256]
{
    __shared__ int rowd[32];
    __shared__ int gslot[32];
    __shared__ int lhist[NBLK];
    __shared__ int lbase[NBLK];

    const int t    = threadIdx.x;
    const int w    = t >> 6;
    const int lane = t & 63;
    const int blk  = blockIdx.x;
    const int d    = blk & 63;                // XCD affinity: same-d -> same XCD
    const int task = blk >> 6;                // 0..7
    const int rt   = task >> 2;               // 0..1
    const int ct   = task & 3;                // 0..3
    const int cw   = ct * 64 + w * 16;        // wave's col base
    const int m    = lane & 15;
    const int qd   = lane >> 4;

    const bool isprep = blk < PREP_BLOCKS;

    // loop-invariant B fragments: lane holds B[k=kb*32+qd*8+j][n=cw+m]
    const float* wb = W + ((size_t)d << 16) + (size_t)(qd * 8) * 256 + (cw + m);
    bf16x8 bfrag[8];
    float bias = 0.0f;

    ushort4 bv[8];
    int slot = 0, myd = 0;

    if (isprep) {
        // ---- prep phase A: ballot + convert (rows blk*32 .. blk*32+31) ----
        if (t < NBLK) lhist[t] = 0;
        const int row0 = blk * 32;
#pragma unroll
        for (int i = 0; i < 8; ++i) {
            const int row = row0 + w * 8 + i;
            const float v = onehot[(size_t)row * NBLK + lane];   // coalesced 256B
            const unsigned long long mm = __ballot(v > 0.5f);
            const int dd = (int)__ffsll(mm) - 1;
            if (lane == 0) rowd[w * 8 + i] = dd;
        }
#pragma unroll
        for (int i = 0; i < 8; ++i) {
            const int row = row0 + w * 8 + i;
            const float4 v = ((const float4*)(x + ((size_t)row << 8)))[lane];
            bv[i].x = f2bf(v.x); bv[i].y = f2bf(v.y);
            bv[i].z = f2bf(v.z); bv[i].w = f2bf(v.w);
        }
        __syncthreads();
        if (t < 32) {
            myd  = rowd[t];
            slot = atomicAdd(&lhist[myd], 1);        // LDS atomic
        }
        __syncthreads();
    } else {
        // ---- W prologue overlapped with prep ----
#pragma unroll
        for (int kb = 0; kb < 8; ++kb) {
            const float* wp = wb + (size_t)(kb * 32) * 256;
#pragma unroll
            for (int j = 0; j < 8; ++j)
                bfrag[kb][j] = (short)f2bf(wp[j * 256]);
        }
        bias = Bw[d * 256 + cw + m];
    }
    if (blk == 0 && t < NBLK) counts[t * CPAD] = 0;   // replaces memset dispatch

    cg::this_grid().sync();   // #1: counts zeroed, local hists final

    if (isprep) {
        // ---- prep phase B: global slot assignment + stores ----
        if (t < NBLK && lhist[t] > 0)
            lbase[t] = atomicAdd(&counts[t * CPAD], lhist[t]);
        __syncthreads();
        const int row0 = blk * 32;
        if (t < 32) {
            const int g = lbase[myd] + slot;         // global bucket slot
            gslot[t] = g;
            if (g < BCAP) buckets[myd * BCAP + g] = row0 + t;
        }
        __syncthreads();
        // store rows bucket-ordered: 512B contiguous per row
#pragma unroll
        for (int i = 0; i < 8; ++i) {
            const int idx = w * 8 + i;
            const int gd  = rowd[idx];
            const int g   = gslot[idx];
            if (g < BCAPX)
                *(ushort4*)(xbs + ((size_t)(gd * BCAPX + g) << 8) + lane * 4) = bv[i];
        }
        // prep blocks load their W frags now (L2-warm from same-d siblings)
#pragma unroll
        for (int kb = 0; kb < 8; ++kb) {
            const float* wp = wb + (size_t)(kb * 32) * 256;
#pragma unroll
            for (int j = 0; j < 8; ++j)
                bfrag[kb][j] = (short)f2bf(wp[j * 256]);
        }
        bias = Bw[d * 256 + cw + m];
        __threadfence();   // release buckets/xbs before grid-wide acquire
    }

    cg::this_grid().sync();   // #2: buckets/xbs/counts visible device-wide

    // ---- compute: 8 blocks per d (2 row-tiles x 4 col-tiles) ----
    int cnt = counts[d * CPAD];
    cnt = cnt < BCAPX ? cnt : BCAPX;
    if (rt * 32 >= cnt) return;

    const int* bkt = buckets + d * BCAP;
    const unsigned short* xd = xbs + ((size_t)(d * BCAPX) << 8);

    for (int base = rt * 32; base < cnt; base += 64) {
        const int i0 = base + m;
        const int i1 = base + 16 + m;
        const int ic0 = i0 < cnt ? i0 : cnt - 1;
        const int ic1 = i1 < cnt ? i1 : cnt - 1;
        const unsigned short* xp0 = xd + ((size_t)ic0 << 8) + qd * 8;
        const unsigned short* xp1 = xd + ((size_t)ic1 << 8) + qd * 8;

        int rid0[4], rid1[4];
#pragma unroll
        for (int reg = 0; reg < 4; ++reg) {
            const int rl0 = base + qd * 4 + reg;
            const int rl1 = base + 16 + qd * 4 + reg;
            rid0[reg] = bkt[rl0 < cnt ? rl0 : cnt - 1];
            rid1[reg] = bkt[rl1 < cnt ? rl1 : cnt - 1];
        }

        f32x4 acc0 = {bias, bias, bias, bias};
        f32x4 acc1 = {bias, bias, bias, bias};
#pragma unroll
        for (int kb = 0; kb < 8; ++kb) {
            bf16x8 a0 = *(const bf16x8*)(xp0 + kb * 32);
            acc0 = __builtin_amdgcn_mfma_f32_16x16x32_bf16(a0, bfrag[kb], acc0, 0, 0, 0);
        }
#pragma unroll
        for (int kb = 0; kb < 8; ++kb) {
            bf16x8 a1 = *(const bf16x8*)(xp1 + kb * 32);
            acc1 = __builtin_amdgcn_mfma_f32_16x16x32_bf16(a1, bfrag[kb], acc1, 0, 0, 0);
        }

#pragma unroll
        for (int reg = 0; reg < 4; ++reg) {
            const int rl0 = base + qd * 4 + reg;
            if (rl0 < cnt) out[((size_t)rid0[reg] << 8) + cw + m] = acc0[reg];
            const int rl1 = base + 16 + qd * 4 + reg;
            if (rl1 < cnt) out[((size_t)rid1[reg] << 8) + cw + m] = acc1[reg];
        }
    }
}

// ---------------- fallback: proven R12 3-dispatch path ----------------

__global__ __launch_bounds__(256) void dd_prep(
    const float* __restrict__ x,
    const float* __restrict__ onehot,
    int* __restrict__ counts,
    int* __restrict__ buckets,
    unsigned short* __restrict__ xbs)
{
    __shared__ int rowd[32];
    __shared__ int gslot[32];
    __shared__ int lhist[NBLK];
    __shared__ int lbase[NBLK];
    const int t = threadIdx.x;
    const int w = t >> 6;
    const int lane = t & 63;
    if (t < NBLK) lhist[t] = 0;

    const int row0 = blockIdx.x * 32;
#pragma unroll
    for (int i = 0; i < 8; ++i) {
        const int row = row0 + w * 8 + i;
        const float v = onehot[(size_t)row * NBLK + lane];
        const unsigned long long mm = __ballot(v > 0.5f);
        const int dd = (int)__ffsll(mm) - 1;
        if (lane == 0) rowd[w * 8 + i] = dd;
    }
    ushort4 bv[8];
#pragma unroll
    for (int i = 0; i < 8; ++i) {
        const int row = row0 + w * 8 + i;
        const float4 v = ((const float4*)(x + ((size_t)row << 8)))[lane];
        bv[i].x = f2bf(v.x); bv[i].y = f2bf(v.y);
        bv[i].z = f2bf(v.z); bv[i].w = f2bf(v.w);
    }
    __syncthreads();

    int d = 0, slot = 0;
    if (t < 32) {
        d = rowd[t];
        slot = atomicAdd(&lhist[d], 1);
    }
    __syncthreads();
    if (t < NBLK && lhist[t] > 0)
        lbase[t] = atomicAdd(&counts[t * CPAD], lhist[t]);
    __syncthreads();
    if (t < 32) {
        const int g = lbase[d] + slot;
        gslot[t] = g;
        if (g < BCAP) buckets[d * BCAP + g] = row0 + t;
    }
    __syncthreads();
#pragma unroll
    for (int i = 0; i < 8; ++i) {
        const int idx = w * 8 + i;
        const int gd  = rowd[idx];
        const int g   = gslot[idx];
        if (g < BCAPX)
            *(ushort4*)(xbs + ((size_t)(gd * BCAPX + g) << 8) + lane * 4) = bv[i];
    }
}

__global__ __launch_bounds__(256) void dd_compute(
    const unsigned short* __restrict__ xbs,
    const float* __restrict__ W,
    const float* __restrict__ Bw,
    const int* __restrict__ counts,
    const int* __restrict__ buckets,
    float* __restrict__ out)
{
    const int t    = threadIdx.x;
    const int lane = t & 63;
    const int w    = t >> 6;
    const int d    = blockIdx.x & 63;
    const int task = blockIdx.x >> 6;
    const int rt   = task >> 2;
    const int ct   = task & 3;
    const int cw   = ct * 64 + w * 16;
    const int m    = lane & 15;
    const int qd   = lane >> 4;

    int cnt = counts[d * CPAD];
    cnt = cnt < BCAPX ? cnt : BCAPX;
    if (rt * 32 >= cnt) return;

    const float* wb = W + ((size_t)d << 16) + (size_t)(qd * 8) * 256 + (cw + m);
    bf16x8 bfrag[8];
#pragma unroll
    for (int kb = 0; kb < 8; ++kb) {
        const float* wp = wb + (size_t)(kb * 32) * 256;
#pragma unroll
        for (int j = 0; j < 8; ++j)
            bfrag[kb][j] = (short)f2bf(wp[j * 256]);
    }

    const float bias = Bw[d * 256 + cw + m];
    const int* bkt = buckets + d * BCAP;
    const unsigned short* xd = xbs + ((size_t)(d * BCAPX) << 8);

    for (int base = rt * 32; base < cnt; base += 128) {
        const int i0 = base + m;
        const int i1 = base + 16 + m;
        const int ic0 = i0 < cnt ? i0 : cnt - 1;
        const int ic1 = i1 < cnt ? i1 : cnt - 1;
        const unsigned short* xp0 = xd + ((size_t)ic0 << 8) + qd * 8;
        const unsigned short* xp1 = xd + ((size_t)ic1 << 8) + qd * 8;

        int rid0[4], rid1[4];
#pragma unroll
        for (int reg = 0; reg < 4; ++reg) {
            const int rl0 = base + qd * 4 + reg;
            const int rl1 = base + 16 + qd * 4 + reg;
            rid0[reg] = bkt[rl0 < cnt ? rl0 : cnt - 1];
            rid1[reg] = bkt[rl1 < cnt ? rl1 : cnt - 1];
        }

        f32x4 acc0 = {bias, bias, bias, bias};
        f32x4 acc1 = {bias, bias, bias, bias};
#pragma unroll
        for (int kb = 0; kb < 8; ++kb) {
            bf16x8 a0 = *(const bf16x8*)(xp0 + kb * 32);
            acc0 = __builtin_amdgcn_mfma_f32_16x16x32_bf16(a0, bfrag[kb], acc0, 0, 0, 0);
        }
#pragma unroll
        for (int kb = 0; kb < 8; ++kb) {
            bf16x8 a1 = *(const bf16x8*)(xp1 + kb * 32);
            acc1 = __builtin_amdgcn_mfma_f32_16x16x32_bf16(a1, bfrag[kb], acc1, 0, 0, 0);
        }

#pragma unroll
        for (int reg = 0; reg < 4; ++reg) {
            const int rl0 = base + qd * 4 + reg;
            if (rl0 < cnt) out[((size_t)rid0[reg] << 8) + cw + m] = acc0[reg];
            const int rl1 = base + 16 + qd * 4 + reg;
            if (rl1 < cnt) out[((size_t)rid1[reg] << 8) + cw + m] = acc1[reg];
        }
    }
}

extern "C" void kernel_launch(void* const* d_in, const int* in_sizes, int n_in,
                              void* d_out, int out_size, void* d_ws, size_t ws_size,
                              hipStream_t stream) {
    const float* x      = (const float*)d_in[0];   // [4096, 256]
    const float* onehot = (const float*)d_in[1];   // [4096, 64]
    const float* W      = (const float*)d_in[2];   // [64, 256, 256]
    const float* Bw     = (const float*)d_in[3];   // [64, 256]
    float* out = (float*)d_out;                    // [4096, 256]

    // ws layout: counts 4KB | buckets 256KB | xbs 8MB (64*256 rows * 512B)
    int* counts  = (int*)d_ws;
    int* buckets = (int*)((char*)d_ws + NBLK * CPAD * 4);
    unsigned short* xbs = (unsigned short*)((char*)d_ws + NBLK * CPAD * 4 + NBLK * BCAP * 4);

    // capture-safe host-side guards (no stream ops): cooperative support +
    // occupancy arithmetic for 512 co-resident blocks.
    static int coop_ok = -1;
    if (coop_ok < 0) {
        int dev = 0;
        (void)hipGetDevice(&dev);
        int has_coop = 0;
        (void)hipDeviceGetAttribute(&has_coop, hipDeviceAttributeCooperativeLaunch, dev);
        int ncu = 0;
        (void)hipDeviceGetAttribute(&ncu, hipDeviceAttributeMultiprocessorCount, dev);
        int nb = 0;
        (void)hipOccupancyMaxActiveBlocksPerMultiprocessor(&nb, dd_fused, 256, 0);
        coop_ok = (has_coop && (long)nb * ncu >= 512) ? 1 : 0;
    }

    hipError_t e = hipErrorUnknown;
    if (coop_ok == 1) {
        void* args[] = {(void*)&x, (void*)&onehot, (void*)&W, (void*)&Bw,
                        (void*)&counts, (void*)&buckets, (void*)&xbs, (void*)&out};
        e = hipLaunchCooperativeKernel((const void*)dd_fused, dim3(512), dim3(256),
                                       args, 0, stream);
    }
    if (e != hipSuccess) {
        // proven R12 path
        hipMemsetAsync(counts, 0, NBLK * CPAD * sizeof(int), stream);
        dd_prep<<<128, 256, 0, stream>>>(x, onehot, counts, buckets, xbs);
        dd_compute<<<1024, 256, 0, stream>>>(xbs, W, Bw, counts, buckets, out);
    }
}

// Round 5
// 101.499 us; speedup vs baseline: 1.9306x; 1.9306x over previous
//
#include <hip/hip_runtime.h>

// DisjointDense: out[b] = x[b] @ W[sel[b]] + Bw[sel[b]]
// B=4096, D_IN=256, D_OUT=256, N_DISJOINT=64, all fp32.
//
// R16: R15 structure (2 dispatches, block-local rowlists, no global
// bucketing) with the determinism bug fixed. R15 failed because each block
// built its rowlist via LDS atomicAdd -> per-block permutations differ ->
// row-tile blocks (rt=0..3) cover positions of DIFFERENT permutations ->
// coverage holes (absmax 4.9 = unwritten rows). Fix: ballot/prefix-scan
// compaction. Thread t owns rows t*16..t*16+15; 16-bit match mask +
// popcount, wave __shfl_up inclusive scan, wave totals in LDS. Every block
// produces the IDENTICAL ascending-row rowlist. No LDS atomics.
//  - dd_sel: onehot -> sel[4096] bytes (4KB), 128 blocks.
//  - dd_compute: 1024 blocks = [task:4][d:6], d = blk&63 (XCD affinity
//    for W L2 reuse), rt = task>>2 (row-tile, stride 128), ct = task&3.
//    Block tile 32 rows x 64 cols; 4 waves = col-slices of 16.
//    A-frags gather x rows fp32 + in-reg bf16 convert (R12 proved the
//    scattered gather is not a bottleneck). Numerics identical to R12.

#define NBLK 64

typedef __attribute__((ext_vector_type(8))) short bf16x8;
typedef __attribute__((ext_vector_type(4))) float f32x4;

__device__ __forceinline__ unsigned short f2bf(float f) {
    unsigned u = __float_as_uint(f);
    u += 0x7FFFu + ((u >> 16) & 1u);       // round-to-nearest-even
    return (unsigned short)(u >> 16);
}

// 128 blocks x 256 threads; wave handles 8 rows: ballot over onehot row,
// lane0 writes sel byte.
__global__ __launch_bounds__(256) void dd_sel(
    const float* __restrict__ onehot,   // [4096, 64]
    unsigned char* __restrict__ sel)    // [4096]
{
    const int t = threadIdx.x;
    const int w = t >> 6;
    const int lane = t & 63;
    const int row0 = blockIdx.x * 32;
#pragma unroll
    for (int i = 0; i < 8; ++i) {
        const int row = row0 + w * 8 + i;
        const float v = onehot[(size_t)row * NBLK + lane];   // coalesced 256B
        const unsigned long long mm = __ballot(v > 0.5f);
        const int dd = (int)__ffsll(mm) - 1;
        if (lane == 0) sel[row] = (unsigned char)dd;
    }
}

// 1024 blocks: [task:4][d:6]. Rowlist built deterministically in LDS.
__global__ __launch_bounds__(256, 4) void dd_compute(
    const float* __restrict__ x,              // [4096, 256] fp32
    const unsigned char* __restrict__ sel,    // [4096]
    const float* __restrict__ W,              // [64, 256, 256] (d, k, col)
    const float* __restrict__ Bw,             // [64, 256]
    float* __restrict__ out)                  // [4096, 256]
{
    __shared__ int rowlist[4096];             // worst-case capacity (16KB)
    __shared__ int wtot[4];

    const int t    = threadIdx.x;
    const int lane = t & 63;
    const int w    = t >> 6;                  // wave = col-slice
    const int d    = blockIdx.x & 63;
    const int task = blockIdx.x >> 6;         // 0..15
    const int rt   = task >> 2;               // 0..3
    const int ct   = task & 3;                // 0..3
    const int cw   = ct * 64 + w * 16;        // wave's col base
    const int m    = lane & 15;
    const int qd   = lane >> 4;

    // one coalesced 16B load per thread covers all 4096 sel bytes
    const int4 sv = ((const int4*)sel)[t];

    // loop-invariant B fragments straight from fp32 W:
    // lane holds B[k=kb*32+qd*8+j][n=cw+m]
    const float* wb = W + ((size_t)d << 16) + (size_t)(qd * 8) * 256 + (cw + m);
    bf16x8 bfrag[8];
#pragma unroll
    for (int kb = 0; kb < 8; ++kb) {
        const float* wp = wb + (size_t)(kb * 32) * 256;
#pragma unroll
        for (int j = 0; j < 8; ++j)
            bfrag[kb][j] = (short)f2bf(wp[j * 256]);
    }
    const float bias = Bw[d * 256 + cw + m];

    // ---- deterministic rowlist compaction (identical in every block) ----
    // thread t owns rows t*16 .. t*16+15
    unsigned mym = 0;
#pragma unroll
    for (int jw = 0; jw < 4; ++jw) {
        const int word = (&sv.x)[jw];
#pragma unroll
        for (int b = 0; b < 4; ++b) {
            const int s = (word >> (8 * b)) & 255;
            if (s == d) mym |= 1u << (jw * 4 + b);
        }
    }
    const int cnt_t = __popc(mym);
    // wave-level inclusive scan of cnt_t
    int scan = cnt_t;
#pragma unroll
    for (int off = 1; off < 64; off <<= 1) {
        const int v = __shfl_up(scan, off, 64);
        if (lane >= off) scan += v;
    }
    if (lane == 63) wtot[w] = scan;
    __syncthreads();
    int wbase = 0;
#pragma unroll
    for (int i = 0; i < 4; ++i) wbase += (i < w) ? wtot[i] : 0;
    const int cnt = wtot[0] + wtot[1] + wtot[2] + wtot[3];
    // write this thread's matches at its exclusive offset (ascending rows)
    int pos = wbase + scan - cnt_t;
    unsigned mm = mym;
    while (mm) {
        const int b = __ffs(mm) - 1;
        mm &= mm - 1;
        rowlist[pos++] = t * 16 + b;
    }
    __syncthreads();

    if (rt * 32 >= cnt) return;

    for (int base = rt * 32; base < cnt; base += 128) {
        const int i0 = base + m;
        const int i1 = base + 16 + m;
        const int r0 = rowlist[i0 < cnt ? i0 : cnt - 1];
        const int r1 = rowlist[i1 < cnt ? i1 : cnt - 1];

        // out row-ids from LDS (prefetched before MFMA chain)
        int rid0[4], rid1[4];
#pragma unroll
        for (int reg = 0; reg < 4; ++reg) {
            const int rl0 = base + qd * 4 + reg;
            const int rl1 = base + 16 + qd * 4 + reg;
            rid0[reg] = rowlist[rl0 < cnt ? rl0 : cnt - 1];
            rid1[reg] = rowlist[rl1 < cnt ? rl1 : cnt - 1];
        }

        // A fragments: fp32 gather + in-reg bf16 convert
        const float* xp0 = x + ((size_t)r0 << 8) + qd * 8;
        const float* xp1 = x + ((size_t)r1 << 8) + qd * 8;

        f32x4 acc0 = {bias, bias, bias, bias};
        f32x4 acc1 = {bias, bias, bias, bias};
#pragma unroll
        for (int kb = 0; kb < 8; ++kb) {
            const float4 lo = *(const float4*)(xp0 + kb * 32);
            const float4 hi = *(const float4*)(xp0 + kb * 32 + 4);
            bf16x8 a0;
            a0[0] = (short)f2bf(lo.x); a0[1] = (short)f2bf(lo.y);
            a0[2] = (short)f2bf(lo.z); a0[3] = (short)f2bf(lo.w);
            a0[4] = (short)f2bf(hi.x); a0[5] = (short)f2bf(hi.y);
            a0[6] = (short)f2bf(hi.z); a0[7] = (short)f2bf(hi.w);
            acc0 = __builtin_amdgcn_mfma_f32_16x16x32_bf16(a0, bfrag[kb], acc0, 0, 0, 0);
        }
#pragma unroll
        for (int kb = 0; kb < 8; ++kb) {
            const float4 lo = *(const float4*)(xp1 + kb * 32);
            const float4 hi = *(const float4*)(xp1 + kb * 32 + 4);
            bf16x8 a1;
            a1[0] = (short)f2bf(lo.x); a1[1] = (short)f2bf(lo.y);
            a1[2] = (short)f2bf(lo.z); a1[3] = (short)f2bf(lo.w);
            a1[4] = (short)f2bf(hi.x); a1[5] = (short)f2bf(hi.y);
            a1[6] = (short)f2bf(hi.z); a1[7] = (short)f2bf(hi.w);
            acc1 = __builtin_amdgcn_mfma_f32_16x16x32_bf16(a1, bfrag[kb], acc1, 0, 0, 0);
        }

        // stores: C/D row = qd*4+reg, col = m
#pragma unroll
        for (int reg = 0; reg < 4; ++reg) {
            const int rl0 = base + qd * 4 + reg;
            if (rl0 < cnt) out[((size_t)rid0[reg] << 8) + cw + m] = acc0[reg];
            const int rl1 = base + 16 + qd * 4 + reg;
            if (rl1 < cnt) out[((size_t)rid1[reg] << 8) + cw + m] = acc1[reg];
        }
    }
}

extern "C" void kernel_launch(void* const* d_in, const int* in_sizes, int n_in,
                              void* d_out, int out_size, void* d_ws, size_t ws_size,
                              hipStream_t stream) {
    const float* x      = (const float*)d_in[0];   // [4096, 256]
    const float* onehot = (const float*)d_in[1];   // [4096, 64]
    const float* W      = (const float*)d_in[2];   // [64, 256, 256]
    const float* Bw     = (const float*)d_in[3];   // [64, 256]
    float* out = (float*)d_out;                    // [4096, 256]

    // ws layout: sel 4KB
    unsigned char* sel = (unsigned char*)d_ws;

    dd_sel<<<128, 256, 0, stream>>>(onehot, sel);
    dd_compute<<<1024, 256, 0, stream>>>(x, sel, W, Bw, out);
}

// Round 6
// 84.825 us; speedup vs baseline: 2.3101x; 1.1966x over previous
//
#include <hip/hip_runtime.h>

// DisjointDense: out[b] = x[b] @ W[sel[b]] + Bw[sel[b]]
// B=4096, D_IN=256, D_OUT=256, N_DISJOINT=64, all fp32.
//
// R17: A/B isolating R16's regression. R16 (101.5us vs R12's 87) kept the
// 2-dispatch local-rowlist structure but switched the A-path to fp32 gather
// + 128 in-reg f2bf converts per lane per iter (2x A-bytes + 16-VALU chain
// ahead of each MFMA). R17 restores the PROVEN bf16 A-path (R8/R12):
//  - dd_prep (128 blocks): onehot -> sel[4096] bytes via ballot AND
//    x -> xb bf16 row-order (no buckets/atomics/counts/memset; no LDS).
//  - dd_compute (1024 blocks = [task:4][d:6], d = blk&63 XCD affinity):
//    R16's deterministic ballot/prefix-scan rowlist (identical in every
//    block -> no coverage holes) + R12's bf16x8 A-gather from xb.
// Decision rule: if this lands >=86 (no win vs R12), 2-vs-3 dispatch is a
// wash and the ~41us chain + ~45us harness poison fill is the floor.

#define NBLK 64

typedef __attribute__((ext_vector_type(8))) short bf16x8;
typedef __attribute__((ext_vector_type(4))) float f32x4;

__device__ __forceinline__ unsigned short f2bf(float f) {
    unsigned u = __float_as_uint(f);
    u += 0x7FFFu + ((u >> 16) & 1u);       // round-to-nearest-even
    return (unsigned short)(u >> 16);
}

// 128 blocks x 256 threads; wave handles 8 rows: ballot -> sel byte,
// float4 load -> ushort4 bf16 store (row-order, 512B/row contiguous).
__global__ __launch_bounds__(256) void dd_prep(
    const float* __restrict__ x,        // [4096, 256]
    const float* __restrict__ onehot,   // [4096, 64]
    unsigned char* __restrict__ sel,    // [4096]
    unsigned short* __restrict__ xb)    // [4096, 256] bf16 row-order
{
    const int t = threadIdx.x;
    const int w = t >> 6;
    const int lane = t & 63;
    const int row0 = blockIdx.x * 32;
#pragma unroll
    for (int i = 0; i < 8; ++i) {
        const int row = row0 + w * 8 + i;
        const float v = onehot[(size_t)row * NBLK + lane];   // coalesced 256B
        const unsigned long long mm = __ballot(v > 0.5f);
        const int dd = (int)__ffsll(mm) - 1;
        if (lane == 0) sel[row] = (unsigned char)dd;
    }
#pragma unroll
    for (int i = 0; i < 8; ++i) {
        const int row = row0 + w * 8 + i;
        const float4 v = ((const float4*)(x + ((size_t)row << 8)))[lane];
        ushort4 b;
        b.x = f2bf(v.x); b.y = f2bf(v.y); b.z = f2bf(v.z); b.w = f2bf(v.w);
        *(ushort4*)(xb + ((size_t)row << 8) + lane * 4) = b;
    }
}

// 1024 blocks: [task:4][d:6]. Deterministic rowlist (identical in every
// block); bf16 A-gather; B-frags loop-invariant from fp32 W.
__global__ __launch_bounds__(256, 4) void dd_compute(
    const unsigned short* __restrict__ xb,    // [4096, 256] bf16
    const unsigned char* __restrict__ sel,    // [4096]
    const float* __restrict__ W,              // [64, 256, 256] (d, k, col)
    const float* __restrict__ Bw,             // [64, 256]
    float* __restrict__ out)                  // [4096, 256]
{
    __shared__ int rowlist[4096];             // worst-case capacity (16KB)
    __shared__ int wtot[4];

    const int t    = threadIdx.x;
    const int lane = t & 63;
    const int w    = t >> 6;                  // wave = col-slice
    const int d    = blockIdx.x & 63;
    const int task = blockIdx.x >> 6;         // 0..15
    const int rt   = task >> 2;               // 0..3
    const int ct   = task & 3;                // 0..3
    const int cw   = ct * 64 + w * 16;        // wave's col base
    const int m    = lane & 15;
    const int qd   = lane >> 4;

    // one coalesced 16B load per thread covers all 4096 sel bytes
    const int4 sv = ((const int4*)sel)[t];

    // loop-invariant B fragments straight from fp32 W:
    // lane holds B[k=kb*32+qd*8+j][n=cw+m]
    const float* wb = W + ((size_t)d << 16) + (size_t)(qd * 8) * 256 + (cw + m);
    bf16x8 bfrag[8];
#pragma unroll
    for (int kb = 0; kb < 8; ++kb) {
        const float* wp = wb + (size_t)(kb * 32) * 256;
#pragma unroll
        for (int j = 0; j < 8; ++j)
            bfrag[kb][j] = (short)f2bf(wp[j * 256]);
    }
    const float bias = Bw[d * 256 + cw + m];

    // ---- deterministic rowlist compaction (identical in every block) ----
    // thread t owns rows t*16 .. t*16+15
    unsigned mym = 0;
#pragma unroll
    for (int jw = 0; jw < 4; ++jw) {
        const int word = (&sv.x)[jw];
#pragma unroll
        for (int b = 0; b < 4; ++b) {
            const int s = (word >> (8 * b)) & 255;
            if (s == d) mym |= 1u << (jw * 4 + b);
        }
    }
    const int cnt_t = __popc(mym);
    // wave-level inclusive scan of cnt_t
    int scan = cnt_t;
#pragma unroll
    for (int off = 1; off < 64; off <<= 1) {
        const int v = __shfl_up(scan, off, 64);
        if (lane >= off) scan += v;
    }
    if (lane == 63) wtot[w] = scan;
    __syncthreads();
    int wbase = 0;
#pragma unroll
    for (int i = 0; i < 4; ++i) wbase += (i < w) ? wtot[i] : 0;
    const int cnt = wtot[0] + wtot[1] + wtot[2] + wtot[3];
    // write this thread's matches at its exclusive offset (ascending rows)
    int pos = wbase + scan - cnt_t;
    unsigned mm = mym;
    while (mm) {
        const int b = __ffs(mm) - 1;
        mm &= mm - 1;
        rowlist[pos++] = t * 16 + b;
    }
    __syncthreads();

    if (rt * 32 >= cnt) return;

    for (int base = rt * 32; base < cnt; base += 128) {
        const int i0 = base + m;
        const int i1 = base + 16 + m;
        const int r0 = rowlist[i0 < cnt ? i0 : cnt - 1];
        const int r1 = rowlist[i1 < cnt ? i1 : cnt - 1];

        // out row-ids from LDS (prefetched before MFMA chain)
        int rid0[4], rid1[4];
#pragma unroll
        for (int reg = 0; reg < 4; ++reg) {
            const int rl0 = base + qd * 4 + reg;
            const int rl1 = base + 16 + qd * 4 + reg;
            rid0[reg] = rowlist[rl0 < cnt ? rl0 : cnt - 1];
            rid1[reg] = rowlist[rl1 < cnt ? rl1 : cnt - 1];
        }

        // A fragments: direct 16B bf16 loads, rows r0/r1, k = kb*32 + qd*8
        const unsigned short* xp0 = xb + ((size_t)r0 << 8) + qd * 8;
        const unsigned short* xp1 = xb + ((size_t)r1 << 8) + qd * 8;

        f32x4 acc0 = {bias, bias, bias, bias};
        f32x4 acc1 = {bias, bias, bias, bias};
#pragma unroll
        for (int kb = 0; kb < 8; ++kb) {
            bf16x8 a0 = *(const bf16x8*)(xp0 + kb * 32);
            acc0 = __builtin_amdgcn_mfma_f32_16x16x32_bf16(a0, bfrag[kb], acc0, 0, 0, 0);
        }
#pragma unroll
        for (int kb = 0; kb < 8; ++kb) {
            bf16x8 a1 = *(const bf16x8*)(xp1 + kb * 32);
            acc1 = __builtin_amdgcn_mfma_f32_16x16x32_bf16(a1, bfrag[kb], acc1, 0, 0, 0);
        }

        // stores: C/D row = qd*4+reg, col = m
#pragma unroll
        for (int reg = 0; reg < 4; ++reg) {
            const int rl0 = base + qd * 4 + reg;
            if (rl0 < cnt) out[((size_t)rid0[reg] << 8) + cw + m] = acc0[reg];
            const int rl1 = base + 16 + qd * 4 + reg;
            if (rl1 < cnt) out[((size_t)rid1[reg] << 8) + cw + m] = acc1[reg];
        }
    }
}

extern "C" void kernel_launch(void* const* d_in, const int* in_sizes, int n_in,
                              void* d_out, int out_size, void* d_ws, size_t ws_size,
                              hipStream_t stream) {
    const float* x      = (const float*)d_in[0];   // [4096, 256]
    const float* onehot = (const float*)d_in[1];   // [4096, 64]
    const float* W      = (const float*)d_in[2];   // [64, 256, 256]
    const float* Bw     = (const float*)d_in[3];   // [64, 256]
    float* out = (float*)d_out;                    // [4096, 256]

    // ws layout: sel 4KB | xb 2MB
    unsigned char* sel = (unsigned char*)d_ws;
    unsigned short* xb = (unsigned short*)((char*)d_ws + 4096);

    dd_prep<<<128, 256, 0, stream>>>(x, onehot, sel, xb);
    dd_compute<<<1024, 256, 0, stream>>>(xb, sel, W, Bw, out);
}